// Round 6
// baseline (1109.819 us; speedup 1.0000x reference)
//
#include <hip/hip_runtime.h>
#include <math.h>

#define BB 2
#define LL 1024
#define DIN_ 512
#define DM_ 1024
#define NL_ 4
#define EE 2048
#define NN 16
#define RR 64
#define KK 4

#define NC 32   // scan chunks
#define CT 32   // timesteps per chunk (NC*CT == LL)

typedef unsigned short ushort_t;
typedef unsigned int uint_t;

using frag_ab = __attribute__((ext_vector_type(8))) short;
using frag_cd = __attribute__((ext_vector_type(4))) float;

__device__ __forceinline__ float softplus_f(float x) {
    return fmaxf(x, 0.f) + log1pf(expf(-fabsf(x)));
}
__device__ __forceinline__ float silu_fast(float x) {
    return x / (1.f + __expf(-x));
}
__device__ __forceinline__ float bf2f(ushort_t x) {
    return __uint_as_float((uint_t)x << 16);
}
__device__ __forceinline__ ushort_t f2bf(float x) {
    uint_t u = __float_as_uint(x);
    uint_t r = (u + 0x7fffu + ((u >> 16) & 1u)) >> 16;   // RNE
    return (ushort_t)r;
}
__device__ __forceinline__ uint_t f2bf2(float lo, float hi) {
    return (uint_t)f2bf(lo) | ((uint_t)f2bf(hi) << 16);
}
__device__ __forceinline__ void gload_lds16(const void* g, void* l) {
    __builtin_amdgcn_global_load_lds(
        (const __attribute__((address_space(1))) void*)g,
        (__attribute__((address_space(3))) void*)l, 16, 0, 0);
}

// ---------------------------------------------------------------------------
// Fused fp32 -> bf16 convert over 6 segments (1 launch).
// R5 post-mortem: all three "optimizations" (wider stores, grid-stride,
// unroll) REGRESSED vs the simple one-unit/thread version (44.2 us, occ 66%).
// Reverted to that version.  ~3.6 TB/s logical for mixed fp32-read/bf16-write
// is near this op's practical floor; no further work here.
// ---------------------------------------------------------------------------
struct CvtArgs {
    const float* src[6];
    ushort_t* dst[6];
    int cum[7];   // cumulative 8-float-unit counts; cum[0]=0
};

__global__ __launch_bounds__(256) void cvt_all_kernel(CvtArgs a)
{
    int i = blockIdx.x * 256 + threadIdx.x;
    if (i >= a.cum[6]) return;
    int s = 0;
#pragma unroll
    for (int k = 1; k < 6; k++) s += (i >= a.cum[k]) ? 1 : 0;
    int j = i - a.cum[s];
    const float4* src = (const float4*)a.src[s];
    float4 v0 = src[2 * j];
    float4 v1 = src[2 * j + 1];
    uint4 u;
    u.x = f2bf2(v0.x, v0.y);
    u.y = f2bf2(v0.z, v0.w);
    u.z = f2bf2(v1.x, v1.y);
    u.w = f2bf2(v1.z, v1.w);
    ((uint4*)a.dst[s])[j] = u;
}

// ---------------------------------------------------------------------------
// bf16 MFMA GEMM, BK=64 double-buffered staging, register-carried pointers.
// Tile M=128 x N=NT*16. 256 thr = 2x2 waves; wave = 4m x NT/2 n MFMA tiles.
// Unified LDS: smem[buf] holds (8+NT)*2 frags of 512 shorts; frag F=(G*2+kk)
// (G = m-frag 0..7 | 8+n-frag, kk = k-half). Staged via global_load_lds
// (uniform frag base + lane*16); read back as frag_ab at +lane*8 shorts.
// One __syncthreads per 64 k (32 MFMAs between barriers for NT=8).
// EPI: 0 none, 5 split-K partial store (z -> Cf+z*pstride)
// ---------------------------------------------------------------------------
template <int EPI, int NT, int OUTBF>
__global__ __launch_bounds__(256) void mgemm_kernel(
    void* __restrict__ Cp, const ushort_t* __restrict__ A,
    const ushort_t* __restrict__ W, const float* __restrict__ bias,
    int N, int K, int lda, int ldw, int ldc, int pstride)
{
    __shared__ __attribute__((aligned(16))) ushort_t smem[2][(8 + NT) * 1024];

    const int tid = threadIdx.x;
    const int w = tid >> 6;
    const int lane = tid & 63;
    const int r = lane & 15;
    const int q = lane >> 4;
    const int m0 = blockIdx.y * 128;
    const int n0 = blockIdx.x * (NT * 16);
    const int wm = w >> 1;
    const int wn = w & 1;
    const int NWT = NT / 2;

    frag_cd acc[4][NWT];
#pragma unroll
    for (int i = 0; i < 4; i++)
#pragma unroll
        for (int j = 0; j < NWT; j++)
#pragma unroll
            for (int t = 0; t < 4; t++) acc[i][j][t] = 0.f;

    size_t koff = (EPI == 5) ? (size_t)blockIdx.z * K : 0;
    const ushort_t* Ab = A + (size_t)m0 * lda + koff;
    const ushort_t* Wb = W + (size_t)n0 * ldw + koff;

    // per-wave staging assignments: frag F = w + fi*4, F in [0, (8+NT)*2)
    constexpr int FPW = (8 + NT) * 2 / 4;
    const ushort_t* gp[FPW];
    bool ok[FPW];
#pragma unroll
    for (int fi = 0; fi < FPW; fi++) {
        int F = w + fi * 4;
        int kk = F & 1;
        int G = F >> 1;
        if (G < 8) {
            gp[fi] = Ab + (size_t)(G * 16 + r) * lda + kk * 32 + q * 8;
            ok[fi] = true;
        } else {
            int nt = G - 8;
            ok[fi] = (n0 + nt * 16 + r) < N;
            gp[fi] = Wb + (size_t)(nt * 16 + r) * ldw + kk * 32 + q * 8;
        }
    }

    auto stage = [&](int buf) {
#pragma unroll
        for (int fi = 0; fi < FPW; fi++) {
            if (ok[fi])
                gload_lds16(gp[fi], &smem[buf][(w + fi * 4) * 512]);
            gp[fi] += 64;   // advance one BK=64 tile
        }
    };

    stage(0);
    int buf = 0;
    for (int k0 = 0; k0 < K; k0 += 64) {
        __syncthreads();                       // drains staging into buf
        if (k0 + 64 < K) stage(buf ^ 1);       // async prefetch next tile
#pragma unroll
        for (int kk = 0; kk < 2; kk++) {
            frag_ab af[4], bf[NWT];
#pragma unroll
            for (int i = 0; i < 4; i++)
                af[i] = *(const frag_ab*)(&smem[buf][((wm * 4 + i) * 2 + kk) * 512] + lane * 8);
#pragma unroll
            for (int j = 0; j < NWT; j++)
                bf[j] = *(const frag_ab*)(&smem[buf][((8 + wn * NWT + j) * 2 + kk) * 512] + lane * 8);
#pragma unroll
            for (int i = 0; i < 4; i++)
#pragma unroll
                for (int j = 0; j < NWT; j++)
                    acc[i][j] = __builtin_amdgcn_mfma_f32_16x16x32_bf16(
                        af[i], bf[j], acc[i][j], 0, 0, 0);
        }
        buf ^= 1;
    }

    float* Cf = (float*)Cp;
    ushort_t* Cb = (ushort_t*)Cp;
    float* Cpart = (EPI == 5) ? Cf + (size_t)blockIdx.z * pstride : Cf;
#pragma unroll
    for (int i = 0; i < 4; i++) {
        int mrow = m0 + (wm * 4 + i) * 16 + q * 4;
#pragma unroll
        for (int j = 0; j < NWT; j++) {
            int col = n0 + (wn * NWT + j) * 16 + r;
            if (col >= N) continue;
#pragma unroll
            for (int t = 0; t < 4; t++) {
                float v = acc[i][j][t];
                size_t idx = (size_t)(mrow + t) * ldc + col;
                if (EPI == 5) { Cpart[idx] = v; continue; }
                if (OUTBF) Cb[idx] = f2bf(v);
                else       Cf[idx] = v;
            }
        }
    }
}

// ---------------------------------------------------------------------------
// Fused split-K reduce + optional residual/bias + LayerNorm (D=1024).
// ---------------------------------------------------------------------------
__global__ __launch_bounds__(256) void reduce_ln_kernel(
    float* __restrict__ h, ushort_t* __restrict__ hn,
    const float* __restrict__ parts, int nparts, int pstride4,
    const float* __restrict__ bias,
    const float* __restrict__ w, const float* __restrict__ b, int hasres)
{
    const int row = blockIdx.x;
    const int tid = threadIdx.x;
    const int i4 = row * (DM_ / 4) + tid;

    float4 v = make_float4(0.f, 0.f, 0.f, 0.f);
    if (hasres) v = ((const float4*)h)[i4];
    for (int p = 0; p < nparts; p++) {
        float4 t = ((const float4*)parts)[(size_t)p * pstride4 + i4];
        v.x += t.x; v.y += t.y; v.z += t.z; v.w += t.w;
    }
    if (bias) {
        float4 t = ((const float4*)bias)[tid];
        v.x += t.x; v.y += t.y; v.z += t.z; v.w += t.w;
    }
    ((float4*)h)[i4] = v;

    float s = v.x + v.y + v.z + v.w;
    float sq = v.x * v.x + v.y * v.y + v.z * v.z + v.w * v.w;
#pragma unroll
    for (int off = 32; off; off >>= 1) {
        s += __shfl_down(s, off);
        sq += __shfl_down(sq, off);
    }
    __shared__ float ls[4], lq[4];
    int wid = tid >> 6;
    if ((tid & 63) == 0) { ls[wid] = s; lq[wid] = sq; }
    __syncthreads();
    float S = ls[0] + ls[1] + ls[2] + ls[3];
    float Q = lq[0] + lq[1] + lq[2] + lq[3];
    float mean = S * (1.f / DM_);
    float var = Q * (1.f / DM_) - mean * mean;
    float inv = rsqrtf(var + 1e-5f);
    float4 wv = ((const float4*)w)[tid];
    float4 bv = ((const float4*)b)[tid];
    ushort4 o;
    o.x = f2bf((v.x - mean) * inv * wv.x + bv.x);
    o.y = f2bf((v.y - mean) * inv * wv.y + bv.y);
    o.z = f2bf((v.z - mean) * inv * wv.z + bv.z);
    o.w = f2bf((v.w - mean) * inv * wv.w + bv.w);
    ((ushort4*)hn)[i4] = o;
}

// xdb = sum of 16 xproj partials (fp32).
__global__ __launch_bounds__(256) void reduce_xdb_kernel(
    float* __restrict__ xdb,
    const float* __restrict__ parts, int pstride4, int total4)
{
    int i = blockIdx.x * 256 + threadIdx.x;
    if (i >= total4) return;
    float4 v = make_float4(0.f, 0.f, 0.f, 0.f);
#pragma unroll
    for (int p = 0; p < 16; p++) {
        float4 t = ((const float4*)parts)[(size_t)p * pstride4 + i];
        v.x += t.x; v.y += t.y; v.z += t.z; v.w += t.w;
    }
    ((float4*)xdb)[i] = v;
}

// out = sum of 4 partials + bias (final op projection)
__global__ __launch_bounds__(256) void reduce_bias_kernel(
    float* __restrict__ out, const float* __restrict__ parts,
    const float* __restrict__ bias, int pstride4, int n4, int total4)
{
    int i = blockIdx.x * 256 + threadIdx.x;
    if (i >= total4) return;
    float4 v = ((const float4*)bias)[i % n4];
#pragma unroll
    for (int p = 0; p < 4; p++) {
        float4 t = ((const float4*)parts)[(size_t)p * pstride4 + i];
        v.x += t.x; v.y += t.y; v.z += t.z; v.w += t.w;
    }
    ((float4*)out)[i] = v;
}

// ---------------------------------------------------------------------------
// Causal depthwise conv (K=4), 4 timesteps per thread.
// ---------------------------------------------------------------------------
__global__ __launch_bounds__(256) void conv_silu_kernel(
    ushort_t* __restrict__ xm, const ushort_t* __restrict__ xz,
    const float* __restrict__ cw, const float* __restrict__ cb)
{
    const int e = blockIdx.x * 256 + threadIdx.x;
    const int t0 = blockIdx.y * 4;
    const int b = blockIdx.z;
    const ushort_t* X = xz + (size_t)b * LL * 2 * EE + e;
    float4 w4 = ((const float4*)cw)[e];
    float wk[4] = {w4.x, w4.y, w4.z, w4.w};
    float cbv = cb[e];
    float v[7];
#pragma unroll
    for (int k = 0; k < 7; k++) {
        int t = t0 - 3 + k;
        v[k] = (t >= 0) ? bf2f(X[(size_t)t * 2 * EE]) : 0.f;
    }
    ushort_t* Y = xm + ((size_t)b * LL + t0) * EE + e;
#pragma unroll
    for (int j = 0; j < 4; j++) {
        float acc = cbv;
#pragma unroll
        for (int k = 0; k < 4; k++) acc = fmaf(wk[k], v[j + k], acc);
        Y[(size_t)j * EE] = f2bf(silu_fast(acc));
    }
}

// ---------------------------------------------------------------------------
// Thread-per-channel chunked scan with INLINE dt projection (R6).
// R5 deduction: standalone dt_kernel was still ~36us/layer — its broadcast
// LDS reads are LDS-issue-bound (256 ds_read_b128/wave, shared CU pipe).
// Fold dt into both scan phases: W row per-lane in VGPRs (loaded once);
// x-row loads use wave-uniform global addresses (blockIdx/loop-index only)
// -> compiler scalarizes to s_load on the free scalar pipe.  4 parallel FMA
// accumulators per row.  Same op order as dt_kernel -> bitwise-identical dt.
// Removes the dt dispatch + 48 MB/layer of dt write+read traffic.
// ---------------------------------------------------------------------------
__device__ __forceinline__ float dt_inline(
    const float* __restrict__ xr, const float4* __restrict__ wr, float dbias)
{
    float a0 = 0.f, a1 = 0.f, a2 = 0.f, a3 = 0.f;
#pragma unroll
    for (int k4 = 0; k4 < 16; k4++) {
        float4 xk = *(const float4*)(xr + k4 * 4);   // wave-uniform -> s_load
        float4 wk = wr[k4];
        a0 = fmaf(wk.x, xk.x, a0);
        a1 = fmaf(wk.y, xk.y, a1);
        a2 = fmaf(wk.z, xk.z, a2);
        a3 = fmaf(wk.w, xk.w, a3);
    }
    return softplus_f((a0 + a1) + (a2 + a3) + dbias);
}

__global__ __launch_bounds__(256) void scan_phase1_kernel(
    float* __restrict__ Pg, float* __restrict__ Sg,
    const ushort_t* __restrict__ u, const float* __restrict__ xdb,
    const float* __restrict__ A_log,
    const float* __restrict__ dtW, const float* __restrict__ dtB)
{
    const int tid = threadIdx.x;
    const int e = blockIdx.x * 256 + tid;
    const int c = blockIdx.y;
    const int b = blockIdx.z;
    const int t0 = c * CT;

    __shared__ float Bs[CT][16];
    {
        int tt = tid >> 3;
        int jj = tid & 7;
        if (jj < 4) {
            float4 v = *(const float4*)(xdb + ((size_t)(b * LL + t0 + tt) * 96 + 64 + jj * 4));
            *(float4*)&Bs[tt][jj * 4] = v;
        }
    }

    float4 wr[16];
    const float4* Wr = (const float4*)(dtW + (size_t)e * RR);
#pragma unroll
    for (int i = 0; i < 16; i++) wr[i] = Wr[i];
    const float dbias = dtB[e];

    float Ae[16];
#pragma unroll
    for (int k = 0; k < 4; k++) {
        float4 a = *(const float4*)(A_log + (size_t)e * NN + k * 4);
        Ae[k * 4 + 0] = -__expf(a.x);
        Ae[k * 4 + 1] = -__expf(a.y);
        Ae[k * 4 + 2] = -__expf(a.z);
        Ae[k * 4 + 3] = -__expf(a.w);
    }
    __syncthreads();

    float S[16];
#pragma unroll
    for (int n = 0; n < 16; n++) S[n] = 0.f;
    float Dsum = 0.f;

    const ushort_t* u_p = u + (size_t)(b * LL + t0) * EE + e;
    const float* xrow = xdb + (size_t)(b * LL + t0) * 96;

#pragma unroll 4
    for (int i = 0; i < CT; i++) {
        float dtv = dt_inline(xrow + (size_t)i * 96, wr, dbias);
        float uv = bf2f(u_p[(size_t)i * EE]);
        float dtu = dtv * uv;
        Dsum += dtv;
        float Bv[16];
#pragma unroll
        for (int k = 0; k < 4; k++)
            *(float4*)&Bv[k * 4] = *(const float4*)&Bs[i][k * 4];
#pragma unroll
        for (int n = 0; n < 16; n++) {
            float da = __expf(dtv * Ae[n]);
            S[n] = fmaf(da, S[n], dtu * Bv[n]);
        }
    }

    size_t o = ((size_t)(b * NC + c) * EE + e) * 16;
#pragma unroll
    for (int k = 0; k < 4; k++) {
        float4 p4;
        p4.x = __expf(Dsum * Ae[k * 4 + 0]);
        p4.y = __expf(Dsum * Ae[k * 4 + 1]);
        p4.z = __expf(Dsum * Ae[k * 4 + 2]);
        p4.w = __expf(Dsum * Ae[k * 4 + 3]);
        *(float4*)(Pg + o + k * 4) = p4;
        *(float4*)(Sg + o + k * 4) = *(float4*)&S[k * 4];
    }
}

// Batched combine: load all 32 chunk summaries (independent, latency
// overlapped), register fma chain, independent stores.
__global__ __launch_bounds__(256) void scan_combine_kernel(
    float* __restrict__ Pg, const float* __restrict__ Sg)
{
    const int f = blockIdx.x * 256 + threadIdx.x;
    const int b = blockIdx.y;
    const size_t stride = (size_t)EE * 16;
    const size_t base = (size_t)b * NC * stride + f;

    float P[NC], S[NC];
#pragma unroll
    for (int c = 0; c < NC; c++) {
        P[c] = Pg[base + c * stride];
        S[c] = Sg[base + c * stride];
    }
    float h = 0.f;
#pragma unroll
    for (int c = 0; c < NC; c++) {
        h = fmaf(P[c], h, S[c]);
        P[c] = h;
    }
#pragma unroll
    for (int c = 0; c < NC; c++)
        Pg[base + c * stride] = P[c];
}

__global__ __launch_bounds__(256) void scan_phase2_kernel(
    ushort_t* __restrict__ y, const float* __restrict__ Pg,
    const ushort_t* __restrict__ u, const float* __restrict__ xdb,
    const ushort_t* __restrict__ xz,
    const float* __restrict__ A_log, const float* __restrict__ Dp,
    const float* __restrict__ dtW, const float* __restrict__ dtB)
{
    const int tid = threadIdx.x;
    const int e = blockIdx.x * 256 + tid;
    const int c = blockIdx.y;
    const int b = blockIdx.z;
    const int t0 = c * CT;

    __shared__ float Bs[CT][16], Cs[CT][16];
    {
        int tt = tid >> 3;
        int jj = tid & 7;
        float4 v = *(const float4*)(xdb + ((size_t)(b * LL + t0 + tt) * 96 + 64 + jj * 4));
        if (jj < 4) *(float4*)&Bs[tt][jj * 4] = v;
        else        *(float4*)&Cs[tt][(jj - 4) * 4] = v;
    }

    float4 wr[16];
    const float4* Wr = (const float4*)(dtW + (size_t)e * RR);
#pragma unroll
    for (int i = 0; i < 16; i++) wr[i] = Wr[i];
    const float dbias = dtB[e];

    float Ae[16];
#pragma unroll
    for (int k = 0; k < 4; k++) {
        float4 a = *(const float4*)(A_log + (size_t)e * NN + k * 4);
        Ae[k * 4 + 0] = -__expf(a.x);
        Ae[k * 4 + 1] = -__expf(a.y);
        Ae[k * 4 + 2] = -__expf(a.z);
        Ae[k * 4 + 3] = -__expf(a.w);
    }
    __syncthreads();

    float h[16];
    if (c == 0) {
#pragma unroll
        for (int n = 0; n < 16; n++) h[n] = 0.f;
    } else {
        size_t o = ((size_t)(b * NC + (c - 1)) * EE + e) * 16;
#pragma unroll
        for (int k = 0; k < 4; k++)
            *(float4*)&h[k * 4] = *(const float4*)(Pg + o + k * 4);
    }

    const float Dv = Dp[e];
    const ushort_t* u_p = u + (size_t)(b * LL + t0) * EE + e;
    const ushort_t* zg_p = xz + (size_t)(b * LL + t0) * 2 * EE + EE + e;
    ushort_t* y_p = y + (size_t)(b * LL + t0) * EE + e;
    const float* xrow = xdb + (size_t)(b * LL + t0) * 96;

#pragma unroll 4
    for (int i = 0; i < CT; i++) {
        float dtv = dt_inline(xrow + (size_t)i * 96, wr, dbias);
        float uv = bf2f(u_p[(size_t)i * EE]);
        float zv = bf2f(zg_p[(size_t)i * 2 * EE]);
        float dtu = dtv * uv;
        float Bv[16], Cv[16];
#pragma unroll
        for (int k = 0; k < 4; k++) {
            *(float4*)&Bv[k * 4] = *(const float4*)&Bs[i][k * 4];
            *(float4*)&Cv[k * 4] = *(const float4*)&Cs[i][k * 4];
        }
        float yv = 0.f;
#pragma unroll
        for (int n = 0; n < 16; n++) {
            float da = __expf(dtv * Ae[n]);
            h[n] = fmaf(da, h[n], dtu * Bv[n]);
            yv = fmaf(h[n], Cv[n], yv);
        }
        y_p[(size_t)i * EE] = f2bf((yv + uv * Dv) * silu_fast(zv));
    }
}

// ---------------------------------------------------------------------------
extern "C" void kernel_launch(void* const* d_in, const int* in_sizes, int n_in,
                              void* d_out, int out_size, void* d_ws, size_t ws_size,
                              hipStream_t stream)
{
    const float* x = (const float*)d_in[0];
    const float* ip_w = (const float*)d_in[2];
    const float* ip_b = (const float*)d_in[3];
    const float* ln_w = (const float*)d_in[4];
    const float* ln_b = (const float*)d_in[5];
    const float* inproj_w = (const float*)d_in[6];
    const float* conv_w = (const float*)d_in[7];
    const float* conv_b = (const float*)d_in[8];
    const float* xproj_w = (const float*)d_in[9];
    const float* dtproj_w = (const float*)d_in[10];
    const float* dtproj_b = (const float*)d_in[11];
    const float* A_log = (const float*)d_in[12];
    const float* Dp = (const float*)d_in[13];
    const float* outproj_w = (const float*)d_in[14];
    const float* fnorm_w = (const float*)d_in[15];
    const float* fnorm_b = (const float*)d_in[16];
    const float* op_w = (const float*)d_in[17];
    const float* op_b = (const float*)d_in[18];
    float* out = (float*)d_out;

    const size_t BL = (size_t)BB * LL;   // 2048

    float* fp = (float*)d_ws;
    float* h = fp;           fp += BL * DM_;
    float* xdb = fp;         fp += BL * 96;
    float* parts = fp;       fp += BL * EE;            // split-K partials scratch
    float* Pg = fp;          fp += (size_t)BB * NC * EE * 16;
    float* Sg = fp;          fp += (size_t)BB * NC * EE * 16;
    ushort_t* us = (ushort_t*)fp;
    ushort_t* xb = us;       us += BL * DIN_;
    ushort_t* hnb = us;      us += BL * DM_;
    ushort_t* xzb = us;      us += BL * 2 * EE;
    ushort_t* xm = us;       us += BL * EE;
    ushort_t* yb = us;       us += BL * EE;
    ushort_t* ipwb = us;     us += (size_t)DM_ * DIN_;
    ushort_t* inprojb = us;  us += (size_t)NL_ * 2 * EE * DM_;
    ushort_t* xprojb = us;   us += (size_t)NL_ * 96 * EE;
    ushort_t* outprojb = us; us += (size_t)NL_ * DM_ * EE;
    ushort_t* opwb = us;     us += (size_t)DIN_ * DM_;

    dim3 blk(256);

    // ---- single fused weight/input conversion
    {
        CvtArgs a;
        const float* srcs[6] = {x, ip_w, inproj_w, xproj_w, outproj_w, op_w};
        ushort_t* dsts[6] = {xb, ipwb, inprojb, xprojb, outprojb, opwb};
        size_t ns[6] = {BL * DIN_, (size_t)DM_ * DIN_, (size_t)NL_ * 2 * EE * DM_,
                        (size_t)NL_ * 96 * EE,
                        (size_t)NL_ * DM_ * EE, (size_t)DIN_ * DM_};
        int cum = 0;
        for (int s = 0; s < 6; s++) {
            a.src[s] = srcs[s];
            a.dst[s] = dsts[s];
            a.cum[s] = cum;
            cum += (int)(ns[s] / 8);
        }
        a.cum[6] = cum;
        cvt_all_kernel<<<dim3((cum + 255) / 256), blk, 0, stream>>>(a);
    }

    const int PS_DM = (int)(BL * DM_);    // partial stride, DM-wide outputs

    // ---- ip: partials x2, then fused reduce(+ip_b) + LN[0]
    mgemm_kernel<5, 4, 0><<<dim3(DM_ / 64, BL / 128, 2), blk, 0, stream>>>(
        parts, xb, ipwb, nullptr, DM_, DIN_ / 2, DIN_, DIN_, DM_, PS_DM);
    reduce_ln_kernel<<<dim3(BL), blk, 0, stream>>>(
        h, hnb, parts, 2, PS_DM / 4, ip_b, ln_w, ln_b, 0);

    for (int l = 0; l < NL_; l++) {
        // xz = hn @ inproj^T (N=4096, K=1024), grid 512
        mgemm_kernel<0, 8, 1><<<dim3(2 * EE / 128, BL / 128), blk, 0, stream>>>(
            xzb, hnb, inprojb + (size_t)l * 2 * EE * DM_, nullptr,
            2 * EE, DM_, DM_, DM_, 2 * EE, 0);
        conv_silu_kernel<<<dim3(EE / 256, LL / 4, BB), blk, 0, stream>>>(
            xm, xzb, conv_w + l * EE * KK, conv_b + l * EE);
        // x_dbl partials x16 -> fused reduce (fp32)
        mgemm_kernel<5, 8, 0><<<dim3(1, BL / 128, 16), blk, 0, stream>>>(
            parts, xm, xprojb + (size_t)l * 96 * EE, nullptr,
            96, EE / 16, EE, EE, 96, (int)(BL * 96));
        reduce_xdb_kernel<<<dim3((int)(BL * 96 / 4 + 255) / 256), blk, 0, stream>>>(
            xdb, parts, (int)(BL * 96 / 4), (int)(BL * 96 / 4));

        // scans with inline dt projection (dt_kernel removed)
        scan_phase1_kernel<<<dim3(EE / 256, NC, BB), blk, 0, stream>>>(
            Pg, Sg, xm, xdb, A_log + (size_t)l * EE * NN,
            dtproj_w + (size_t)l * EE * RR, dtproj_b + (size_t)l * EE);
        scan_combine_kernel<<<dim3(EE * 16 / 256, BB), blk, 0, stream>>>(Pg, Sg);
        scan_phase2_kernel<<<dim3(EE / 256, NC, BB), blk, 0, stream>>>(
            yb, Pg, xm, xdb, xzb, A_log + (size_t)l * EE * NN, Dp + l * EE,
            dtproj_w + (size_t)l * EE * RR, dtproj_b + (size_t)l * EE);

        // outproj partials x4, then fused reduce + residual + next LN
        mgemm_kernel<5, 8, 0><<<dim3(DM_ / 128, BL / 128, 4), blk, 0, stream>>>(
            parts, yb, outprojb + (size_t)l * DM_ * EE, nullptr,
            DM_, EE / 4, EE, EE, DM_, PS_DM);
        const float* nw = (l + 1 < NL_) ? ln_w + (l + 1) * DM_ : fnorm_w;
        const float* nb = (l + 1 < NL_) ? ln_b + (l + 1) * DM_ : fnorm_b;
        reduce_ln_kernel<<<dim3(BL), blk, 0, stream>>>(
            h, hnb, parts, 4, PS_DM / 4, nullptr, nw, nb, 1);
    }

    // ---- out = hn @ op_w^T + op_b : partials x4 + fused bias reduce
    mgemm_kernel<5, 4, 0><<<dim3(DIN_ / 64, BL / 128, 4), blk, 0, stream>>>(
        parts, hnb, opwb, nullptr, DIN_, DM_ / 4, DM_, DM_, DIN_, (int)(BL * DIN_));
    reduce_bias_kernel<<<dim3((int)(BL * DIN_ / 4 + 255) / 256), blk, 0, stream>>>(
        out, parts, op_b, (int)(BL * DIN_ / 4), DIN_ / 4, (int)(BL * DIN_ / 4));
}

// Round 8
// 920.586 us; speedup vs baseline: 1.2056x; 1.2056x over previous
//
#include <hip/hip_runtime.h>
#include <math.h>

#define BB 2
#define LL 1024
#define DIN_ 512
#define DM_ 1024
#define NL_ 4
#define EE 2048
#define NN 16
#define RR 64
#define KK 4

#define NC 32   // scan chunks
#define CT 32   // timesteps per chunk (NC*CT == LL)

typedef unsigned short ushort_t;
typedef unsigned int uint_t;

using frag_ab = __attribute__((ext_vector_type(8))) short;
using frag_cd = __attribute__((ext_vector_type(4))) float;

__device__ __forceinline__ float softplus_f(float x) {
    return fmaxf(x, 0.f) + log1pf(expf(-fabsf(x)));
}
__device__ __forceinline__ float silu_fast(float x) {
    return x / (1.f + __expf(-x));
}
__device__ __forceinline__ float bf2f(ushort_t x) {
    return __uint_as_float((uint_t)x << 16);
}
__device__ __forceinline__ ushort_t f2bf(float x) {
    uint_t u = __float_as_uint(x);
    uint_t r = (u + 0x7fffu + ((u >> 16) & 1u)) >> 16;   // RNE
    return (ushort_t)r;
}
__device__ __forceinline__ uint_t f2bf2(float lo, float hi) {
    return (uint_t)f2bf(lo) | ((uint_t)f2bf(hi) << 16);
}
__device__ __forceinline__ void gload_lds16(const void* g, void* l) {
    __builtin_amdgcn_global_load_lds(
        (const __attribute__((address_space(1))) void*)g,
        (__attribute__((address_space(3))) void*)l, 16, 0, 0);
}

// ---------------------------------------------------------------------------
// Fused fp32 -> bf16 convert over 6 segments (1 launch).  ~44us, near its
// practical floor for mixed fp32-read/bf16-write (R3/R4/R5 attempts all
// regressed).  Frozen.
// ---------------------------------------------------------------------------
struct CvtArgs {
    const float* src[6];
    ushort_t* dst[6];
    int cum[7];   // cumulative 8-float-unit counts; cum[0]=0
};

__global__ __launch_bounds__(256) void cvt_all_kernel(CvtArgs a)
{
    int i = blockIdx.x * 256 + threadIdx.x;
    if (i >= a.cum[6]) return;
    int s = 0;
#pragma unroll
    for (int k = 1; k < 6; k++) s += (i >= a.cum[k]) ? 1 : 0;
    int j = i - a.cum[s];
    const float4* src = (const float4*)a.src[s];
    float4 v0 = src[2 * j];
    float4 v1 = src[2 * j + 1];
    uint4 u;
    u.x = f2bf2(v0.x, v0.y);
    u.y = f2bf2(v0.z, v0.w);
    u.z = f2bf2(v1.x, v1.y);
    u.w = f2bf2(v1.z, v1.w);
    ((uint4*)a.dst[s])[j] = u;
}

// ---------------------------------------------------------------------------
// bf16 MFMA GEMM, BK=64 double-buffered staging, register-carried pointers.
// Tile M=128 x N=NT*16. 256 thr = 2x2 waves; wave = 4m x NT/2 n MFMA tiles.
// EPI: 0 none, 5 split-K partial store (z -> Cf+z*pstride)
// ---------------------------------------------------------------------------
template <int EPI, int NT, int OUTBF>
__global__ __launch_bounds__(256) void mgemm_kernel(
    void* __restrict__ Cp, const ushort_t* __restrict__ A,
    const ushort_t* __restrict__ W, const float* __restrict__ bias,
    int N, int K, int lda, int ldw, int ldc, int pstride)
{
    __shared__ __attribute__((aligned(16))) ushort_t smem[2][(8 + NT) * 1024];

    const int tid = threadIdx.x;
    const int w = tid >> 6;
    const int lane = tid & 63;
    const int r = lane & 15;
    const int q = lane >> 4;
    const int m0 = blockIdx.y * 128;
    const int n0 = blockIdx.x * (NT * 16);
    const int wm = w >> 1;
    const int wn = w & 1;
    const int NWT = NT / 2;

    frag_cd acc[4][NWT];
#pragma unroll
    for (int i = 0; i < 4; i++)
#pragma unroll
        for (int j = 0; j < NWT; j++)
#pragma unroll
            for (int t = 0; t < 4; t++) acc[i][j][t] = 0.f;

    size_t koff = (EPI == 5) ? (size_t)blockIdx.z * K : 0;
    const ushort_t* Ab = A + (size_t)m0 * lda + koff;
    const ushort_t* Wb = W + (size_t)n0 * ldw + koff;

    // per-wave staging assignments: frag F = w + fi*4, F in [0, (8+NT)*2)
    constexpr int FPW = (8 + NT) * 2 / 4;
    const ushort_t* gp[FPW];
    bool ok[FPW];
#pragma unroll
    for (int fi = 0; fi < FPW; fi++) {
        int F = w + fi * 4;
        int kk = F & 1;
        int G = F >> 1;
        if (G < 8) {
            gp[fi] = Ab + (size_t)(G * 16 + r) * lda + kk * 32 + q * 8;
            ok[fi] = true;
        } else {
            int nt = G - 8;
            ok[fi] = (n0 + nt * 16 + r) < N;
            gp[fi] = Wb + (size_t)(nt * 16 + r) * ldw + kk * 32 + q * 8;
        }
    }

    auto stage = [&](int buf) {
#pragma unroll
        for (int fi = 0; fi < FPW; fi++) {
            if (ok[fi])
                gload_lds16(gp[fi], &smem[buf][(w + fi * 4) * 512]);
            gp[fi] += 64;   // advance one BK=64 tile
        }
    };

    stage(0);
    int buf = 0;
    for (int k0 = 0; k0 < K; k0 += 64) {
        __syncthreads();                       // drains staging into buf
        if (k0 + 64 < K) stage(buf ^ 1);       // async prefetch next tile
#pragma unroll
        for (int kk = 0; kk < 2; kk++) {
            frag_ab af[4], bf[NWT];
#pragma unroll
            for (int i = 0; i < 4; i++)
                af[i] = *(const frag_ab*)(&smem[buf][((wm * 4 + i) * 2 + kk) * 512] + lane * 8);
#pragma unroll
            for (int j = 0; j < NWT; j++)
                bf[j] = *(const frag_ab*)(&smem[buf][((8 + wn * NWT + j) * 2 + kk) * 512] + lane * 8);
#pragma unroll
            for (int i = 0; i < 4; i++)
#pragma unroll
                for (int j = 0; j < NWT; j++)
                    acc[i][j] = __builtin_amdgcn_mfma_f32_16x16x32_bf16(
                        af[i], bf[j], acc[i][j], 0, 0, 0);
        }
        buf ^= 1;
    }

    float* Cf = (float*)Cp;
    ushort_t* Cb = (ushort_t*)Cp;
    float* Cpart = (EPI == 5) ? Cf + (size_t)blockIdx.z * pstride : Cf;
#pragma unroll
    for (int i = 0; i < 4; i++) {
        int mrow = m0 + (wm * 4 + i) * 16 + q * 4;
#pragma unroll
        for (int j = 0; j < NWT; j++) {
            int col = n0 + (wn * NWT + j) * 16 + r;
            if (col >= N) continue;
#pragma unroll
            for (int t = 0; t < 4; t++) {
                float v = acc[i][j][t];
                size_t idx = (size_t)(mrow + t) * ldc + col;
                if (EPI == 5) { Cpart[idx] = v; continue; }
                if (OUTBF) Cb[idx] = f2bf(v);
                else       Cf[idx] = v;
            }
        }
    }
}

// ---------------------------------------------------------------------------
// dt projection: dt[t][e] = softplus(xdb[t][0:64] . W[e][:] + b[e])
// R6 post-mortem established the R2-R5 version is LDS-issue-bound
// (256 ds_read_b128/wave x 12cyc on the shared CU LDS pipe ~= 20us floor,
// ~40 observed).  R7: 2-way e-register-blocking — each thread owns W rows
// for e and e+256 (128 VGPR), so every staged x ds_read feeds TWO dot
// products (LDS instructions per output halved).  Block = 8 t x 512 e,
// grid (4,256) = 1024 blocks (~3 blocks/CU).  Same per-channel op order
// as before -> bitwise-identical dt.  Stores coalesced (lane = e).
// ---------------------------------------------------------------------------
__global__ __launch_bounds__(256) void dt_kernel(
    float* __restrict__ dtb, const float* __restrict__ xdb,
    const float* __restrict__ W, const float* __restrict__ bias)
{
    const int tid = threadIdx.x;
    const int e0 = blockIdx.x * 512 + tid;      // channel A
    const int e1 = e0 + 256;                    // channel B
    const int t0 = blockIdx.y * 8;              // 8 time-rows per block

    __shared__ float xs[8][64];
    if (tid < 128) {
        int tt = tid >> 4;                      // row 0..7
        int k4 = tid & 15;                      // float4 0..15 within row
        float4 v = *(const float4*)(xdb + (size_t)(t0 + tt) * 96 + k4 * 4);
        *(float4*)&xs[tt][k4 * 4] = v;
    }

    float4 wa[16], wb[16];
    const float4* Wa = (const float4*)(W + (size_t)e0 * RR);
    const float4* Wb = (const float4*)(W + (size_t)e1 * RR);
#pragma unroll
    for (int i = 0; i < 16; i++) { wa[i] = Wa[i]; wb[i] = Wb[i]; }
    const float ba = bias[e0];
    const float bb = bias[e1];
    __syncthreads();

#pragma unroll 2
    for (int t = 0; t < 8; t++) {
        float a0 = 0.f, a1 = 0.f, a2 = 0.f, a3 = 0.f;
        float c0 = 0.f, c1 = 0.f, c2 = 0.f, c3 = 0.f;
#pragma unroll
        for (int k4 = 0; k4 < 16; k4++) {
            float4 xk = *(const float4*)&xs[t][k4 * 4];   // broadcast read
            float4 u = wa[k4];
            float4 v = wb[k4];
            a0 = fmaf(u.x, xk.x, a0);
            a1 = fmaf(u.y, xk.y, a1);
            a2 = fmaf(u.z, xk.z, a2);
            a3 = fmaf(u.w, xk.w, a3);
            c0 = fmaf(v.x, xk.x, c0);
            c1 = fmaf(v.y, xk.y, c1);
            c2 = fmaf(v.z, xk.z, c2);
            c3 = fmaf(v.w, xk.w, c3);
        }
        float* drow = dtb + (size_t)(t0 + t) * EE;
        drow[e0] = softplus_f((a0 + a1) + (a2 + a3) + ba);
        drow[e1] = softplus_f((c0 + c1) + (c2 + c3) + bb);
    }
}

// ---------------------------------------------------------------------------
// Fused split-K reduce + optional residual/bias + LayerNorm (D=1024).
// ---------------------------------------------------------------------------
__global__ __launch_bounds__(256) void reduce_ln_kernel(
    float* __restrict__ h, ushort_t* __restrict__ hn,
    const float* __restrict__ parts, int nparts, int pstride4,
    const float* __restrict__ bias,
    const float* __restrict__ w, const float* __restrict__ b, int hasres)
{
    const int row = blockIdx.x;
    const int tid = threadIdx.x;
    const int i4 = row * (DM_ / 4) + tid;

    float4 v = make_float4(0.f, 0.f, 0.f, 0.f);
    if (hasres) v = ((const float4*)h)[i4];
    for (int p = 0; p < nparts; p++) {
        float4 t = ((const float4*)parts)[(size_t)p * pstride4 + i4];
        v.x += t.x; v.y += t.y; v.z += t.z; v.w += t.w;
    }
    if (bias) {
        float4 t = ((const float4*)bias)[tid];
        v.x += t.x; v.y += t.y; v.z += t.z; v.w += t.w;
    }
    ((float4*)h)[i4] = v;

    float s = v.x + v.y + v.z + v.w;
    float sq = v.x * v.x + v.y * v.y + v.z * v.z + v.w * v.w;
#pragma unroll
    for (int off = 32; off; off >>= 1) {
        s += __shfl_down(s, off);
        sq += __shfl_down(sq, off);
    }
    __shared__ float ls[4], lq[4];
    int wid = tid >> 6;
    if ((tid & 63) == 0) { ls[wid] = s; lq[wid] = sq; }
    __syncthreads();
    float S = ls[0] + ls[1] + ls[2] + ls[3];
    float Q = lq[0] + lq[1] + lq[2] + lq[3];
    float mean = S * (1.f / DM_);
    float var = Q * (1.f / DM_) - mean * mean;
    float inv = rsqrtf(var + 1e-5f);
    float4 wv = ((const float4*)w)[tid];
    float4 bv = ((const float4*)b)[tid];
    ushort4 o;
    o.x = f2bf((v.x - mean) * inv * wv.x + bv.x);
    o.y = f2bf((v.y - mean) * inv * wv.y + bv.y);
    o.z = f2bf((v.z - mean) * inv * wv.z + bv.z);
    o.w = f2bf((v.w - mean) * inv * wv.w + bv.w);
    ((ushort4*)hn)[i4] = o;
}

// xdb = sum of 16 xproj partials (fp32).
__global__ __launch_bounds__(256) void reduce_xdb_kernel(
    float* __restrict__ xdb,
    const float* __restrict__ parts, int pstride4, int total4)
{
    int i = blockIdx.x * 256 + threadIdx.x;
    if (i >= total4) return;
    float4 v = make_float4(0.f, 0.f, 0.f, 0.f);
#pragma unroll
    for (int p = 0; p < 16; p++) {
        float4 t = ((const float4*)parts)[(size_t)p * pstride4 + i];
        v.x += t.x; v.y += t.y; v.z += t.z; v.w += t.w;
    }
    ((float4*)xdb)[i] = v;
}

// out = sum of 4 partials + bias (final op projection)
__global__ __launch_bounds__(256) void reduce_bias_kernel(
    float* __restrict__ out, const float* __restrict__ parts,
    const float* __restrict__ bias, int pstride4, int n4, int total4)
{
    int i = blockIdx.x * 256 + threadIdx.x;
    if (i >= total4) return;
    float4 v = ((const float4*)bias)[i % n4];
#pragma unroll
    for (int p = 0; p < 4; p++) {
        float4 t = ((const float4*)parts)[(size_t)p * pstride4 + i];
        v.x += t.x; v.y += t.y; v.z += t.z; v.w += t.w;
    }
    ((float4*)out)[i] = v;
}

// ---------------------------------------------------------------------------
// Causal depthwise conv (K=4), 4 timesteps per thread.
// ---------------------------------------------------------------------------
__global__ __launch_bounds__(256) void conv_silu_kernel(
    ushort_t* __restrict__ xm, const ushort_t* __restrict__ xz,
    const float* __restrict__ cw, const float* __restrict__ cb)
{
    const int e = blockIdx.x * 256 + threadIdx.x;
    const int t0 = blockIdx.y * 4;
    const int b = blockIdx.z;
    const ushort_t* X = xz + (size_t)b * LL * 2 * EE + e;
    float4 w4 = ((const float4*)cw)[e];
    float wk[4] = {w4.x, w4.y, w4.z, w4.w};
    float cbv = cb[e];
    float v[7];
#pragma unroll
    for (int k = 0; k < 7; k++) {
        int t = t0 - 3 + k;
        v[k] = (t >= 0) ? bf2f(X[(size_t)t * 2 * EE]) : 0.f;
    }
    ushort_t* Y = xm + ((size_t)b * LL + t0) * EE + e;
#pragma unroll
    for (int j = 0; j < 4; j++) {
        float acc = cbv;
#pragma unroll
        for (int k = 0; k < 4; k++) acc = fmaf(wk[k], v[j + k], acc);
        Y[(size_t)j * EE] = f2bf(silu_fast(acc));
    }
}

// ---------------------------------------------------------------------------
// Thread-per-channel chunked scan (R5 structure restored; R6 inline-dt
// fusion regressed 2.8x on scan_phase1 — 512 uniform loads/thread on the
// critical path at 2 blocks/CU).
// ---------------------------------------------------------------------------
__global__ __launch_bounds__(256) void scan_phase1_kernel(
    float* __restrict__ Pg, float* __restrict__ Sg,
    const float* __restrict__ dt, const ushort_t* __restrict__ u,
    const float* __restrict__ xdb, const float* __restrict__ A_log)
{
    const int tid = threadIdx.x;
    const int e = blockIdx.x * 256 + tid;
    const int c = blockIdx.y;
    const int b = blockIdx.z;
    const int t0 = c * CT;

    __shared__ float Bs[CT][16];
    {
        int tt = tid >> 3;
        int jj = tid & 7;
        if (jj < 4) {
            float4 v = *(const float4*)(xdb + ((size_t)(b * LL + t0 + tt) * 96 + 64 + jj * 4));
            *(float4*)&Bs[tt][jj * 4] = v;
        }
    }
    __syncthreads();

    float Ae[16];
#pragma unroll
    for (int k = 0; k < 4; k++) {
        float4 a = *(const float4*)(A_log + (size_t)e * NN + k * 4);
        Ae[k * 4 + 0] = -__expf(a.x);
        Ae[k * 4 + 1] = -__expf(a.y);
        Ae[k * 4 + 2] = -__expf(a.z);
        Ae[k * 4 + 3] = -__expf(a.w);
    }

    float S[16];
#pragma unroll
    for (int n = 0; n < 16; n++) S[n] = 0.f;
    float Dsum = 0.f;

    const float* dt_p = dt + (size_t)(b * LL + t0) * EE + e;
    const ushort_t* u_p = u + (size_t)(b * LL + t0) * EE + e;

    float dtv = dt_p[0];
    float uv = bf2f(u_p[0]);
#pragma unroll 4
    for (int i = 0; i < CT; i++) {
        int ip = (i + 1 < CT) ? i + 1 : i;
        float dtn = dt_p[(size_t)ip * EE];
        float un = bf2f(u_p[(size_t)ip * EE]);
        float dtu = dtv * uv;
        Dsum += dtv;
        float Bv[16];
#pragma unroll
        for (int k = 0; k < 4; k++)
            *(float4*)&Bv[k * 4] = *(const float4*)&Bs[i][k * 4];
#pragma unroll
        for (int n = 0; n < 16; n++) {
            float da = __expf(dtv * Ae[n]);
            S[n] = fmaf(da, S[n], dtu * Bv[n]);
        }
        dtv = dtn; uv = un;
    }

    size_t o = ((size_t)(b * NC + c) * EE + e) * 16;
#pragma unroll
    for (int k = 0; k < 4; k++) {
        float4 p4;
        p4.x = __expf(Dsum * Ae[k * 4 + 0]);
        p4.y = __expf(Dsum * Ae[k * 4 + 1]);
        p4.z = __expf(Dsum * Ae[k * 4 + 2]);
        p4.w = __expf(Dsum * Ae[k * 4 + 3]);
        *(float4*)(Pg + o + k * 4) = p4;
        *(float4*)(Sg + o + k * 4) = *(float4*)&S[k * 4];
    }
}

// Batched combine: load all 32 chunk summaries (independent, latency
// overlapped), register fma chain, independent stores.
__global__ __launch_bounds__(256) void scan_combine_kernel(
    float* __restrict__ Pg, const float* __restrict__ Sg)
{
    const int f = blockIdx.x * 256 + threadIdx.x;
    const int b = blockIdx.y;
    const size_t stride = (size_t)EE * 16;
    const size_t base = (size_t)b * NC * stride + f;

    float P[NC], S[NC];
#pragma unroll
    for (int c = 0; c < NC; c++) {
        P[c] = Pg[base + c * stride];
        S[c] = Sg[base + c * stride];
    }
    float h = 0.f;
#pragma unroll
    for (int c = 0; c < NC; c++) {
        h = fmaf(P[c], h, S[c]);
        P[c] = h;
    }
#pragma unroll
    for (int c = 0; c < NC; c++)
        Pg[base + c * stride] = P[c];
}

__global__ __launch_bounds__(256) void scan_phase2_kernel(
    ushort_t* __restrict__ y, const float* __restrict__ Pg,
    const float* __restrict__ dt, const ushort_t* __restrict__ u,
    const float* __restrict__ xdb, const ushort_t* __restrict__ xz,
    const float* __restrict__ A_log, const float* __restrict__ Dp)
{
    const int tid = threadIdx.x;
    const int e = blockIdx.x * 256 + tid;
    const int c = blockIdx.y;
    const int b = blockIdx.z;
    const int t0 = c * CT;

    __shared__ float Bs[CT][16], Cs[CT][16];
    {
        int tt = tid >> 3;
        int jj = tid & 7;
        float4 v = *(const float4*)(xdb + ((size_t)(b * LL + t0 + tt) * 96 + 64 + jj * 4));
        if (jj < 4) *(float4*)&Bs[tt][jj * 4] = v;
        else        *(float4*)&Cs[tt][(jj - 4) * 4] = v;
    }
    __syncthreads();

    float Ae[16];
#pragma unroll
    for (int k = 0; k < 4; k++) {
        float4 a = *(const float4*)(A_log + (size_t)e * NN + k * 4);
        Ae[k * 4 + 0] = -__expf(a.x);
        Ae[k * 4 + 1] = -__expf(a.y);
        Ae[k * 4 + 2] = -__expf(a.z);
        Ae[k * 4 + 3] = -__expf(a.w);
    }

    float h[16];
    if (c == 0) {
#pragma unroll
        for (int n = 0; n < 16; n++) h[n] = 0.f;
    } else {
        size_t o = ((size_t)(b * NC + (c - 1)) * EE + e) * 16;
#pragma unroll
        for (int k = 0; k < 4; k++)
            *(float4*)&h[k * 4] = *(const float4*)(Pg + o + k * 4);
    }

    const float Dv = Dp[e];
    const float* dt_p = dt + (size_t)(b * LL + t0) * EE + e;
    const ushort_t* u_p = u + (size_t)(b * LL + t0) * EE + e;
    const ushort_t* zg_p = xz + (size_t)(b * LL + t0) * 2 * EE + EE + e;
    ushort_t* y_p = y + (size_t)(b * LL + t0) * EE + e;

    float dtv = dt_p[0];
    float uv = bf2f(u_p[0]);
    float zv = bf2f(zg_p[0]);
#pragma unroll 4
    for (int i = 0; i < CT; i++) {
        int ip = (i + 1 < CT) ? i + 1 : i;
        float dtn = dt_p[(size_t)ip * EE];
        float un = bf2f(u_p[(size_t)ip * EE]);
        float zn = bf2f(zg_p[(size_t)ip * 2 * EE]);
        float dtu = dtv * uv;
        float Bv[16], Cv[16];
#pragma unroll
        for (int k = 0; k < 4; k++) {
            *(float4*)&Bv[k * 4] = *(const float4*)&Bs[i][k * 4];
            *(float4*)&Cv[k * 4] = *(const float4*)&Cs[i][k * 4];
        }
        float yv = 0.f;
#pragma unroll
        for (int n = 0; n < 16; n++) {
            float da = __expf(dtv * Ae[n]);
            h[n] = fmaf(da, h[n], dtu * Bv[n]);
            yv = fmaf(h[n], Cv[n], yv);
        }
        y_p[(size_t)i * EE] = f2bf((yv + uv * Dv) * silu_fast(zv));
        dtv = dtn; uv = un; zv = zn;
    }
}

// ---------------------------------------------------------------------------
extern "C" void kernel_launch(void* const* d_in, const int* in_sizes, int n_in,
                              void* d_out, int out_size, void* d_ws, size_t ws_size,
                              hipStream_t stream)
{
    const float* x = (const float*)d_in[0];
    const float* ip_w = (const float*)d_in[2];
    const float* ip_b = (const float*)d_in[3];
    const float* ln_w = (const float*)d_in[4];
    const float* ln_b = (const float*)d_in[5];
    const float* inproj_w = (const float*)d_in[6];
    const float* conv_w = (const float*)d_in[7];
    const float* conv_b = (const float*)d_in[8];
    const float* xproj_w = (const float*)d_in[9];
    const float* dtproj_w = (const float*)d_in[10];
    const float* dtproj_b = (const float*)d_in[11];
    const float* A_log = (const float*)d_in[12];
    const float* Dp = (const float*)d_in[13];
    const float* outproj_w = (const float*)d_in[14];
    const float* fnorm_w = (const float*)d_in[15];
    const float* fnorm_b = (const float*)d_in[16];
    const float* op_w = (const float*)d_in[17];
    const float* op_b = (const float*)d_in[18];
    float* out = (float*)d_out;

    const size_t BL = (size_t)BB * LL;   // 2048

    float* fp = (float*)d_ws;
    float* h = fp;           fp += BL * DM_;
    float* xdb = fp;         fp += BL * 96;
    float* dtb = fp;         fp += BL * EE;            // also: parts region base
    float* Pg = fp;          fp += (size_t)BB * NC * EE * 16;
    float* Sg = fp;          fp += (size_t)BB * NC * EE * 16;
    float* parts = dtb;      // overlay: dead whenever partials live
    ushort_t* us = (ushort_t*)fp;
    ushort_t* xb = us;       us += BL * DIN_;
    ushort_t* hnb = us;      us += BL * DM_;
    ushort_t* xzb = us;      us += BL * 2 * EE;
    ushort_t* xm = us;       us += BL * EE;
    ushort_t* yb = us;       us += BL * EE;
    ushort_t* ipwb = us;     us += (size_t)DM_ * DIN_;
    ushort_t* inprojb = us;  us += (size_t)NL_ * 2 * EE * DM_;
    ushort_t* xprojb = us;   us += (size_t)NL_ * 96 * EE;
    ushort_t* outprojb = us; us += (size_t)NL_ * DM_ * EE;
    ushort_t* opwb = us;     us += (size_t)DIN_ * DM_;

    dim3 blk(256);

    // ---- single fused weight/input conversion
    {
        CvtArgs a;
        const float* srcs[6] = {x, ip_w, inproj_w, xproj_w, outproj_w, op_w};
        ushort_t* dsts[6] = {xb, ipwb, inprojb, xprojb, outprojb, opwb};
        size_t ns[6] = {BL * DIN_, (size_t)DM_ * DIN_, (size_t)NL_ * 2 * EE * DM_,
                        (size_t)NL_ * 96 * EE,
                        (size_t)NL_ * DM_ * EE, (size_t)DIN_ * DM_};
        int cum = 0;
        for (int s = 0; s < 6; s++) {
            a.src[s] = srcs[s];
            a.dst[s] = dsts[s];
            a.cum[s] = cum;
            cum += (int)(ns[s] / 8);
        }
        a.cum[6] = cum;
        cvt_all_kernel<<<dim3((cum + 255) / 256), blk, 0, stream>>>(a);
    }

    const int PS_DM = (int)(BL * DM_);    // partial stride, DM-wide outputs

    // ---- ip: partials x2, then fused reduce(+ip_b) + LN[0]
    mgemm_kernel<5, 4, 0><<<dim3(DM_ / 64, BL / 128, 2), blk, 0, stream>>>(
        parts, xb, ipwb, nullptr, DM_, DIN_ / 2, DIN_, DIN_, DM_, PS_DM);
    reduce_ln_kernel<<<dim3(BL), blk, 0, stream>>>(
        h, hnb, parts, 2, PS_DM / 4, ip_b, ln_w, ln_b, 0);

    for (int l = 0; l < NL_; l++) {
        // xz = hn @ inproj^T (N=4096, K=1024), grid 512
        mgemm_kernel<0, 8, 1><<<dim3(2 * EE / 128, BL / 128), blk, 0, stream>>>(
            xzb, hnb, inprojb + (size_t)l * 2 * EE * DM_, nullptr,
            2 * EE, DM_, DM_, DM_, 2 * EE, 0);
        conv_silu_kernel<<<dim3(EE / 256, LL / 4, BB), blk, 0, stream>>>(
            xm, xzb, conv_w + l * EE * KK, conv_b + l * EE);
        // x_dbl partials x16 -> fused reduce (fp32)
        mgemm_kernel<5, 8, 0><<<dim3(1, BL / 128, 16), blk, 0, stream>>>(
            parts, xm, xprojb + (size_t)l * 96 * EE, nullptr,
            96, EE / 16, EE, EE, 96, (int)(BL * 96));
        reduce_xdb_kernel<<<dim3((int)(BL * 96 / 4 + 255) / 256), blk, 0, stream>>>(
            xdb, parts, (int)(BL * 96 / 4), (int)(BL * 96 / 4));
        // dt = softplus(x_dbl[:, :R] @ dtproj^T + b) — 2-way e-blocked
        dt_kernel<<<dim3(EE / 512, BL / 8), blk, 0, stream>>>(
            dtb, xdb, dtproj_w + (size_t)l * EE * RR, dtproj_b + (size_t)l * EE);

        scan_phase1_kernel<<<dim3(EE / 256, NC, BB), blk, 0, stream>>>(
            Pg, Sg, dtb, xm, xdb, A_log + (size_t)l * EE * NN);
        scan_combine_kernel<<<dim3(EE * 16 / 256, BB), blk, 0, stream>>>(Pg, Sg);
        scan_phase2_kernel<<<dim3(EE / 256, NC, BB), blk, 0, stream>>>(
            yb, Pg, dtb, xm, xdb, xzb, A_log + (size_t)l * EE * NN, Dp + l * EE);

        // outproj partials x4, then fused reduce + residual + next LN
        mgemm_kernel<5, 8, 0><<<dim3(DM_ / 128, BL / 128, 4), blk, 0, stream>>>(
            parts, yb, outprojb + (size_t)l * DM_ * EE, nullptr,
            DM_, EE / 4, EE, EE, DM_, PS_DM);
        const float* nw = (l + 1 < NL_) ? ln_w + (l + 1) * DM_ : fnorm_w;
        const float* nb = (l + 1 < NL_) ? ln_b + (l + 1) * DM_ : fnorm_b;
        reduce_ln_kernel<<<dim3(BL), blk, 0, stream>>>(
            h, hnb, parts, 4, PS_DM / 4, nullptr, nw, nb, 1);
    }

    // ---- out = hn @ op_w^T + op_b : partials x4 + fused bias reduce
    mgemm_kernel<5, 4, 0><<<dim3(DIN_ / 64, BL / 128, 4), blk, 0, stream>>>(
        parts, hnb, opwb, nullptr, DIN_, DM_ / 4, DM_, DM_, DIN_, (int)(BL * DIN_));
    reduce_bias_kernel<<<dim3((int)(BL * DIN_ / 4 + 255) / 256), blk, 0, stream>>>(
        out, parts, op_b, (int)(BL * DIN_ / 4), DIN_ / 4, (int)(BL * DIN_ / 4));
}

// Round 9
// 853.387 us; speedup vs baseline: 1.3005x; 1.0787x over previous
//
#include <hip/hip_runtime.h>
#include <math.h>

#define BB 2
#define LL 1024
#define DIN_ 512
#define DM_ 1024
#define NL_ 4
#define EE 2048
#define NN 16
#define RR 64
#define KK 4

#define NC 32   // scan chunks
#define CT 32   // timesteps per chunk (NC*CT == LL)

typedef unsigned short ushort_t;
typedef unsigned int uint_t;

using frag_ab = __attribute__((ext_vector_type(8))) short;
using frag_cd = __attribute__((ext_vector_type(4))) float;

__device__ __forceinline__ float softplus_f(float x) {
    return fmaxf(x, 0.f) + log1pf(expf(-fabsf(x)));
}
__device__ __forceinline__ float silu_fast(float x) {
    return x / (1.f + __expf(-x));
}
__device__ __forceinline__ float bf2f(ushort_t x) {
    return __uint_as_float((uint_t)x << 16);
}
__device__ __forceinline__ ushort_t f2bf(float x) {
    uint_t u = __float_as_uint(x);
    uint_t r = (u + 0x7fffu + ((u >> 16) & 1u)) >> 16;   // RNE
    return (ushort_t)r;
}
__device__ __forceinline__ uint_t f2bf2(float lo, float hi) {
    return (uint_t)f2bf(lo) | ((uint_t)f2bf(hi) << 16);
}
__device__ __forceinline__ void gload_lds16(const void* g, void* l) {
    __builtin_amdgcn_global_load_lds(
        (const __attribute__((address_space(1))) void*)g,
        (__attribute__((address_space(3))) void*)l, 16, 0, 0);
}

// ---------------------------------------------------------------------------
// Fused fp32 -> bf16 convert over 7 segments (1 launch).  ~44us, near its
// practical floor (R3/R4/R5 attempts all regressed).  dtproj re-added for
// the MFMA dt kernel.  Frozen otherwise.
// ---------------------------------------------------------------------------
struct CvtArgs {
    const float* src[7];
    ushort_t* dst[7];
    int cum[8];   // cumulative 8-float-unit counts; cum[0]=0
};

__global__ __launch_bounds__(256) void cvt_all_kernel(CvtArgs a)
{
    int i = blockIdx.x * 256 + threadIdx.x;
    if (i >= a.cum[7]) return;
    int s = 0;
#pragma unroll
    for (int k = 1; k < 7; k++) s += (i >= a.cum[k]) ? 1 : 0;
    int j = i - a.cum[s];
    const float4* src = (const float4*)a.src[s];
    float4 v0 = src[2 * j];
    float4 v1 = src[2 * j + 1];
    uint4 u;
    u.x = f2bf2(v0.x, v0.y);
    u.y = f2bf2(v0.z, v0.w);
    u.z = f2bf2(v1.x, v1.y);
    u.w = f2bf2(v1.z, v1.w);
    ((uint4*)a.dst[s])[j] = u;
}

// ---------------------------------------------------------------------------
// bf16 MFMA GEMM, BK=64 double-buffered staging, register-carried pointers.
// Tile M=128 x N=NT*16. 256 thr = 2x2 waves; wave = 4m x NT/2 n MFMA tiles.
// EPI: 0 none, 5 split-K partial store (z -> Cf+z*pstride)
// ---------------------------------------------------------------------------
template <int EPI, int NT, int OUTBF>
__global__ __launch_bounds__(256) void mgemm_kernel(
    void* __restrict__ Cp, const ushort_t* __restrict__ A,
    const ushort_t* __restrict__ W, const float* __restrict__ bias,
    int N, int K, int lda, int ldw, int ldc, int pstride)
{
    __shared__ __attribute__((aligned(16))) ushort_t smem[2][(8 + NT) * 1024];

    const int tid = threadIdx.x;
    const int w = tid >> 6;
    const int lane = tid & 63;
    const int r = lane & 15;
    const int q = lane >> 4;
    const int m0 = blockIdx.y * 128;
    const int n0 = blockIdx.x * (NT * 16);
    const int wm = w >> 1;
    const int wn = w & 1;
    const int NWT = NT / 2;

    frag_cd acc[4][NWT];
#pragma unroll
    for (int i = 0; i < 4; i++)
#pragma unroll
        for (int j = 0; j < NWT; j++)
#pragma unroll
            for (int t = 0; t < 4; t++) acc[i][j][t] = 0.f;

    size_t koff = (EPI == 5) ? (size_t)blockIdx.z * K : 0;
    const ushort_t* Ab = A + (size_t)m0 * lda + koff;
    const ushort_t* Wb = W + (size_t)n0 * ldw + koff;

    // per-wave staging assignments: frag F = w + fi*4, F in [0, (8+NT)*2)
    constexpr int FPW = (8 + NT) * 2 / 4;
    const ushort_t* gp[FPW];
    bool ok[FPW];
#pragma unroll
    for (int fi = 0; fi < FPW; fi++) {
        int F = w + fi * 4;
        int kk = F & 1;
        int G = F >> 1;
        if (G < 8) {
            gp[fi] = Ab + (size_t)(G * 16 + r) * lda + kk * 32 + q * 8;
            ok[fi] = true;
        } else {
            int nt = G - 8;
            ok[fi] = (n0 + nt * 16 + r) < N;
            gp[fi] = Wb + (size_t)(nt * 16 + r) * ldw + kk * 32 + q * 8;
        }
    }

    auto stage = [&](int buf) {
#pragma unroll
        for (int fi = 0; fi < FPW; fi++) {
            if (ok[fi])
                gload_lds16(gp[fi], &smem[buf][(w + fi * 4) * 512]);
            gp[fi] += 64;   // advance one BK=64 tile
        }
    };

    stage(0);
    int buf = 0;
    for (int k0 = 0; k0 < K; k0 += 64) {
        __syncthreads();                       // drains staging into buf
        if (k0 + 64 < K) stage(buf ^ 1);       // async prefetch next tile
#pragma unroll
        for (int kk = 0; kk < 2; kk++) {
            frag_ab af[4], bf[NWT];
#pragma unroll
            for (int i = 0; i < 4; i++)
                af[i] = *(const frag_ab*)(&smem[buf][((wm * 4 + i) * 2 + kk) * 512] + lane * 8);
#pragma unroll
            for (int j = 0; j < NWT; j++)
                bf[j] = *(const frag_ab*)(&smem[buf][((8 + wn * NWT + j) * 2 + kk) * 512] + lane * 8);
#pragma unroll
            for (int i = 0; i < 4; i++)
#pragma unroll
                for (int j = 0; j < NWT; j++)
                    acc[i][j] = __builtin_amdgcn_mfma_f32_16x16x32_bf16(
                        af[i], bf[j], acc[i][j], 0, 0, 0);
        }
        buf ^= 1;
    }

    float* Cf = (float*)Cp;
    ushort_t* Cb = (ushort_t*)Cp;
    float* Cpart = (EPI == 5) ? Cf + (size_t)blockIdx.z * pstride : Cf;
#pragma unroll
    for (int i = 0; i < 4; i++) {
        int mrow = m0 + (wm * 4 + i) * 16 + q * 4;
#pragma unroll
        for (int j = 0; j < NWT; j++) {
            int col = n0 + (wn * NWT + j) * 16 + r;
            if (col >= N) continue;
#pragma unroll
            for (int t = 0; t < 4; t++) {
                float v = acc[i][j][t];
                size_t idx = (size_t)(mrow + t) * ldc + col;
                if (EPI == 5) { Cpart[idx] = v; continue; }
                if (OUTBF) Cb[idx] = f2bf(v);
                else       Cf[idx] = v;
            }
        }
    }
}

// ---------------------------------------------------------------------------
// dt projection via MFMA (R9).  Four VALU/LDS dt designs all measured
// ~38-48us — the invariant cost is a dependent ds_read->FMA chain at low
// occupancy (LDS latency ~120cyc exposed).  MFMA eats K=64 in 2 instr per
// 16x16 tile with no per-element chain.  dt = xdbb(2048x96,:64) @
// dtprojb^T(2048x64) + bias -> softplus, fp32 out.  Numerics identical to
// R0's mgemm<EPI=2> path, which PASSED (absmax 0.015625).
// Tile 64x64, 4 waves (2x2), 16 frags of 512 shorts staged one-per-wave
// via global_load_lds (mgemm's exact frag idiom), single barrier, 8 MFMA
// per wave.  Grid (32,32)=1024 blocks, LDS 16KB, low VGPR.
// ---------------------------------------------------------------------------
__global__ __launch_bounds__(256) void dtmm_kernel(
    float* __restrict__ dtb, const ushort_t* __restrict__ A,
    const ushort_t* __restrict__ W, const float* __restrict__ bias)
{
    __shared__ __attribute__((aligned(16))) ushort_t smem[16 * 512];

    const int tid = threadIdx.x;
    const int w = tid >> 6;
    const int lane = tid & 63;
    const int r = lane & 15;
    const int q = lane >> 4;
    const int m0 = blockIdx.y * 64;   // t-rows
    const int n0 = blockIdx.x * 64;   // e-cols
    const int wm = w >> 1;
    const int wn = w & 1;

    // stage 16 frags, 4 per wave: F = w + fi*4; kk = F&1, G = F>>1
    // G<4: A group (16 rows of xdbb, lda=96); G>=4: B group (W rows, ldw=64)
#pragma unroll
    for (int fi = 0; fi < 4; fi++) {
        int F = w + fi * 4;
        int kk = F & 1;
        int G = F >> 1;
        const ushort_t* src;
        if (G < 4)
            src = A + (size_t)(m0 + G * 16 + r) * 96 + kk * 32 + q * 8;
        else
            src = W + (size_t)(n0 + (G - 4) * 16 + r) * RR + kk * 32 + q * 8;
        gload_lds16(src, &smem[F * 512]);
    }
    __syncthreads();

    frag_cd acc[2][2];
#pragma unroll
    for (int i = 0; i < 2; i++)
#pragma unroll
        for (int j = 0; j < 2; j++)
#pragma unroll
            for (int t = 0; t < 4; t++) acc[i][j][t] = 0.f;

#pragma unroll
    for (int kk = 0; kk < 2; kk++) {
        frag_ab af[2], bf[2];
#pragma unroll
        for (int i = 0; i < 2; i++)
            af[i] = *(const frag_ab*)(&smem[((wm * 2 + i) * 2 + kk) * 512] + lane * 8);
#pragma unroll
        for (int j = 0; j < 2; j++)
            bf[j] = *(const frag_ab*)(&smem[((4 + wn * 2 + j) * 2 + kk) * 512] + lane * 8);
#pragma unroll
        for (int i = 0; i < 2; i++)
#pragma unroll
            for (int j = 0; j < 2; j++)
                acc[i][j] = __builtin_amdgcn_mfma_f32_16x16x32_bf16(
                    af[i], bf[j], acc[i][j], 0, 0, 0);
    }

#pragma unroll
    for (int i = 0; i < 2; i++) {
        int mrow = m0 + (wm * 2 + i) * 16 + q * 4;
#pragma unroll
        for (int j = 0; j < 2; j++) {
            int col = n0 + (wn * 2 + j) * 16 + r;
            float bv = bias[col];
#pragma unroll
            for (int t = 0; t < 4; t++)
                dtb[(size_t)(mrow + t) * EE + col] = softplus_f(acc[i][j][t] + bv);
        }
    }
}

// ---------------------------------------------------------------------------
// Fused split-K reduce + optional residual/bias + LayerNorm (D=1024).
// ---------------------------------------------------------------------------
__global__ __launch_bounds__(256) void reduce_ln_kernel(
    float* __restrict__ h, ushort_t* __restrict__ hn,
    const float* __restrict__ parts, int nparts, int pstride4,
    const float* __restrict__ bias,
    const float* __restrict__ w, const float* __restrict__ b, int hasres)
{
    const int row = blockIdx.x;
    const int tid = threadIdx.x;
    const int i4 = row * (DM_ / 4) + tid;

    float4 v = make_float4(0.f, 0.f, 0.f, 0.f);
    if (hasres) v = ((const float4*)h)[i4];
    for (int p = 0; p < nparts; p++) {
        float4 t = ((const float4*)parts)[(size_t)p * pstride4 + i4];
        v.x += t.x; v.y += t.y; v.z += t.z; v.w += t.w;
    }
    if (bias) {
        float4 t = ((const float4*)bias)[tid];
        v.x += t.x; v.y += t.y; v.z += t.z; v.w += t.w;
    }
    ((float4*)h)[i4] = v;

    float s = v.x + v.y + v.z + v.w;
    float sq = v.x * v.x + v.y * v.y + v.z * v.z + v.w * v.w;
#pragma unroll
    for (int off = 32; off; off >>= 1) {
        s += __shfl_down(s, off);
        sq += __shfl_down(sq, off);
    }
    __shared__ float ls[4], lq[4];
    int wid = tid >> 6;
    if ((tid & 63) == 0) { ls[wid] = s; lq[wid] = sq; }
    __syncthreads();
    float S = ls[0] + ls[1] + ls[2] + ls[3];
    float Q = lq[0] + lq[1] + lq[2] + lq[3];
    float mean = S * (1.f / DM_);
    float var = Q * (1.f / DM_) - mean * mean;
    float inv = rsqrtf(var + 1e-5f);
    float4 wv = ((const float4*)w)[tid];
    float4 bv = ((const float4*)b)[tid];
    ushort4 o;
    o.x = f2bf((v.x - mean) * inv * wv.x + bv.x);
    o.y = f2bf((v.y - mean) * inv * wv.y + bv.y);
    o.z = f2bf((v.z - mean) * inv * wv.z + bv.z);
    o.w = f2bf((v.w - mean) * inv * wv.w + bv.w);
    ((ushort4*)hn)[i4] = o;
}

// xdb = sum of 16 xproj partials; writes fp32 + bf16 copies (bf16 feeds dtmm).
__global__ __launch_bounds__(256) void reduce_xdb_kernel(
    float* __restrict__ xdb, ushort_t* __restrict__ xdbb,
    const float* __restrict__ parts, int pstride4, int total4)
{
    int i = blockIdx.x * 256 + threadIdx.x;
    if (i >= total4) return;
    float4 v = make_float4(0.f, 0.f, 0.f, 0.f);
#pragma unroll
    for (int p = 0; p < 16; p++) {
        float4 t = ((const float4*)parts)[(size_t)p * pstride4 + i];
        v.x += t.x; v.y += t.y; v.z += t.z; v.w += t.w;
    }
    ((float4*)xdb)[i] = v;
    ushort4 u;
    u.x = f2bf(v.x); u.y = f2bf(v.y); u.z = f2bf(v.z); u.w = f2bf(v.w);
    ((ushort4*)xdbb)[i] = u;
}

// out = sum of 4 partials + bias (final op projection)
__global__ __launch_bounds__(256) void reduce_bias_kernel(
    float* __restrict__ out, const float* __restrict__ parts,
    const float* __restrict__ bias, int pstride4, int n4, int total4)
{
    int i = blockIdx.x * 256 + threadIdx.x;
    if (i >= total4) return;
    float4 v = ((const float4*)bias)[i % n4];
#pragma unroll
    for (int p = 0; p < 4; p++) {
        float4 t = ((const float4*)parts)[(size_t)p * pstride4 + i];
        v.x += t.x; v.y += t.y; v.z += t.z; v.w += t.w;
    }
    ((float4*)out)[i] = v;
}

// ---------------------------------------------------------------------------
// Causal depthwise conv (K=4), 4 timesteps per thread.
// ---------------------------------------------------------------------------
__global__ __launch_bounds__(256) void conv_silu_kernel(
    ushort_t* __restrict__ xm, const ushort_t* __restrict__ xz,
    const float* __restrict__ cw, const float* __restrict__ cb)
{
    const int e = blockIdx.x * 256 + threadIdx.x;
    const int t0 = blockIdx.y * 4;
    const int b = blockIdx.z;
    const ushort_t* X = xz + (size_t)b * LL * 2 * EE + e;
    float4 w4 = ((const float4*)cw)[e];
    float wk[4] = {w4.x, w4.y, w4.z, w4.w};
    float cbv = cb[e];
    float v[7];
#pragma unroll
    for (int k = 0; k < 7; k++) {
        int t = t0 - 3 + k;
        v[k] = (t >= 0) ? bf2f(X[(size_t)t * 2 * EE]) : 0.f;
    }
    ushort_t* Y = xm + ((size_t)b * LL + t0) * EE + e;
#pragma unroll
    for (int j = 0; j < 4; j++) {
        float acc = cbv;
#pragma unroll
        for (int k = 0; k < 4; k++) acc = fmaf(wk[k], v[j + k], acc);
        Y[(size_t)j * EE] = f2bf(silu_fast(acc));
    }
}

// ---------------------------------------------------------------------------
// Thread-per-channel chunked scan (R5 structure).
// ---------------------------------------------------------------------------
__global__ __launch_bounds__(256) void scan_phase1_kernel(
    float* __restrict__ Pg, float* __restrict__ Sg,
    const float* __restrict__ dt, const ushort_t* __restrict__ u,
    const float* __restrict__ xdb, const float* __restrict__ A_log)
{
    const int tid = threadIdx.x;
    const int e = blockIdx.x * 256 + tid;
    const int c = blockIdx.y;
    const int b = blockIdx.z;
    const int t0 = c * CT;

    __shared__ float Bs[CT][16];
    {
        int tt = tid >> 3;
        int jj = tid & 7;
        if (jj < 4) {
            float4 v = *(const float4*)(xdb + ((size_t)(b * LL + t0 + tt) * 96 + 64 + jj * 4));
            *(float4*)&Bs[tt][jj * 4] = v;
        }
    }
    __syncthreads();

    float Ae[16];
#pragma unroll
    for (int k = 0; k < 4; k++) {
        float4 a = *(const float4*)(A_log + (size_t)e * NN + k * 4);
        Ae[k * 4 + 0] = -__expf(a.x);
        Ae[k * 4 + 1] = -__expf(a.y);
        Ae[k * 4 + 2] = -__expf(a.z);
        Ae[k * 4 + 3] = -__expf(a.w);
    }

    float S[16];
#pragma unroll
    for (int n = 0; n < 16; n++) S[n] = 0.f;
    float Dsum = 0.f;

    const float* dt_p = dt + (size_t)(b * LL + t0) * EE + e;
    const ushort_t* u_p = u + (size_t)(b * LL + t0) * EE + e;

    float dtv = dt_p[0];
    float uv = bf2f(u_p[0]);
#pragma unroll 4
    for (int i = 0; i < CT; i++) {
        int ip = (i + 1 < CT) ? i + 1 : i;
        float dtn = dt_p[(size_t)ip * EE];
        float un = bf2f(u_p[(size_t)ip * EE]);
        float dtu = dtv * uv;
        Dsum += dtv;
        float Bv[16];
#pragma unroll
        for (int k = 0; k < 4; k++)
            *(float4*)&Bv[k * 4] = *(const float4*)&Bs[i][k * 4];
#pragma unroll
        for (int n = 0; n < 16; n++) {
            float da = __expf(dtv * Ae[n]);
            S[n] = fmaf(da, S[n], dtu * Bv[n]);
        }
        dtv = dtn; uv = un;
    }

    size_t o = ((size_t)(b * NC + c) * EE + e) * 16;
#pragma unroll
    for (int k = 0; k < 4; k++) {
        float4 p4;
        p4.x = __expf(Dsum * Ae[k * 4 + 0]);
        p4.y = __expf(Dsum * Ae[k * 4 + 1]);
        p4.z = __expf(Dsum * Ae[k * 4 + 2]);
        p4.w = __expf(Dsum * Ae[k * 4 + 3]);
        *(float4*)(Pg + o + k * 4) = p4;
        *(float4*)(Sg + o + k * 4) = *(float4*)&S[k * 4];
    }
}

// Batched combine: load all 32 chunk summaries (independent, latency
// overlapped), register fma chain, independent stores.
__global__ __launch_bounds__(256) void scan_combine_kernel(
    float* __restrict__ Pg, const float* __restrict__ Sg)
{
    const int f = blockIdx.x * 256 + threadIdx.x;
    const int b = blockIdx.y;
    const size_t stride = (size_t)EE * 16;
    const size_t base = (size_t)b * NC * stride + f;

    float P[NC], S[NC];
#pragma unroll
    for (int c = 0; c < NC; c++) {
        P[c] = Pg[base + c * stride];
        S[c] = Sg[base + c * stride];
    }
    float h = 0.f;
#pragma unroll
    for (int c = 0; c < NC; c++) {
        h = fmaf(P[c], h, S[c]);
        P[c] = h;
    }
#pragma unroll
    for (int c = 0; c < NC; c++)
        Pg[base + c * stride] = P[c];
}

__global__ __launch_bounds__(256) void scan_phase2_kernel(
    ushort_t* __restrict__ y, const float* __restrict__ Pg,
    const float* __restrict__ dt, const ushort_t* __restrict__ u,
    const float* __restrict__ xdb, const ushort_t* __restrict__ xz,
    const float* __restrict__ A_log, const float* __restrict__ Dp)
{
    const int tid = threadIdx.x;
    const int e = blockIdx.x * 256 + tid;
    const int c = blockIdx.y;
    const int b = blockIdx.z;
    const int t0 = c * CT;

    __shared__ float Bs[CT][16], Cs[CT][16];
    {
        int tt = tid >> 3;
        int jj = tid & 7;
        float4 v = *(const float4*)(xdb + ((size_t)(b * LL + t0 + tt) * 96 + 64 + jj * 4));
        if (jj < 4) *(float4*)&Bs[tt][jj * 4] = v;
        else        *(float4*)&Cs[tt][(jj - 4) * 4] = v;
    }
    __syncthreads();

    float Ae[16];
#pragma unroll
    for (int k = 0; k < 4; k++) {
        float4 a = *(const float4*)(A_log + (size_t)e * NN + k * 4);
        Ae[k * 4 + 0] = -__expf(a.x);
        Ae[k * 4 + 1] = -__expf(a.y);
        Ae[k * 4 + 2] = -__expf(a.z);
        Ae[k * 4 + 3] = -__expf(a.w);
    }

    float h[16];
    if (c == 0) {
#pragma unroll
        for (int n = 0; n < 16; n++) h[n] = 0.f;
    } else {
        size_t o = ((size_t)(b * NC + (c - 1)) * EE + e) * 16;
#pragma unroll
        for (int k = 0; k < 4; k++)
            *(float4*)&h[k * 4] = *(const float4*)(Pg + o + k * 4);
    }

    const float Dv = Dp[e];
    const float* dt_p = dt + (size_t)(b * LL + t0) * EE + e;
    const ushort_t* u_p = u + (size_t)(b * LL + t0) * EE + e;
    const ushort_t* zg_p = xz + (size_t)(b * LL + t0) * 2 * EE + EE + e;
    ushort_t* y_p = y + (size_t)(b * LL + t0) * EE + e;

    float dtv = dt_p[0];
    float uv = bf2f(u_p[0]);
    float zv = bf2f(zg_p[0]);
#pragma unroll 4
    for (int i = 0; i < CT; i++) {
        int ip = (i + 1 < CT) ? i + 1 : i;
        float dtn = dt_p[(size_t)ip * EE];
        float un = bf2f(u_p[(size_t)ip * EE]);
        float zn = bf2f(zg_p[(size_t)ip * 2 * EE]);
        float dtu = dtv * uv;
        float Bv[16], Cv[16];
#pragma unroll
        for (int k = 0; k < 4; k++) {
            *(float4*)&Bv[k * 4] = *(const float4*)&Bs[i][k * 4];
            *(float4*)&Cv[k * 4] = *(const float4*)&Cs[i][k * 4];
        }
        float yv = 0.f;
#pragma unroll
        for (int n = 0; n < 16; n++) {
            float da = __expf(dtv * Ae[n]);
            h[n] = fmaf(da, h[n], dtu * Bv[n]);
            yv = fmaf(h[n], Cv[n], yv);
        }
        y_p[(size_t)i * EE] = f2bf((yv + uv * Dv) * silu_fast(zv));
        dtv = dtn; uv = un; zv = zn;
    }
}

// ---------------------------------------------------------------------------
extern "C" void kernel_launch(void* const* d_in, const int* in_sizes, int n_in,
                              void* d_out, int out_size, void* d_ws, size_t ws_size,
                              hipStream_t stream)
{
    const float* x = (const float*)d_in[0];
    const float* ip_w = (const float*)d_in[2];
    const float* ip_b = (const float*)d_in[3];
    const float* ln_w = (const float*)d_in[4];
    const float* ln_b = (const float*)d_in[5];
    const float* inproj_w = (const float*)d_in[6];
    const float* conv_w = (const float*)d_in[7];
    const float* conv_b = (const float*)d_in[8];
    const float* xproj_w = (const float*)d_in[9];
    const float* dtproj_w = (const float*)d_in[10];
    const float* dtproj_b = (const float*)d_in[11];
    const float* A_log = (const float*)d_in[12];
    const float* Dp = (const float*)d_in[13];
    const float* outproj_w = (const float*)d_in[14];
    const float* fnorm_w = (const float*)d_in[15];
    const float* fnorm_b = (const float*)d_in[16];
    const float* op_w = (const float*)d_in[17];
    const float* op_b = (const float*)d_in[18];
    float* out = (float*)d_out;

    const size_t BL = (size_t)BB * LL;   // 2048

    float* fp = (float*)d_ws;
    float* h = fp;           fp += BL * DM_;
    float* xdb = fp;         fp += BL * 96;
    float* dtb = fp;         fp += BL * EE;            // also: parts region base
    float* Pg = fp;          fp += (size_t)BB * NC * EE * 16;
    float* Sg = fp;          fp += (size_t)BB * NC * EE * 16;
    float* parts = dtb;      // overlay: dead whenever partials live
    ushort_t* us = (ushort_t*)fp;
    ushort_t* xb = us;       us += BL * DIN_;
    ushort_t* hnb = us;      us += BL * DM_;
    ushort_t* xzb = us;      us += BL * 2 * EE;
    ushort_t* xm = us;       us += BL * EE;
    ushort_t* xdbb = us;     us += BL * 96;
    ushort_t* yb = us;       us += BL * EE;
    ushort_t* ipwb = us;     us += (size_t)DM_ * DIN_;
    ushort_t* inprojb = us;  us += (size_t)NL_ * 2 * EE * DM_;
    ushort_t* xprojb = us;   us += (size_t)NL_ * 96 * EE;
    ushort_t* dtprojb = us;  us += (size_t)NL_ * EE * RR;
    ushort_t* outprojb = us; us += (size_t)NL_ * DM_ * EE;
    ushort_t* opwb = us;     us += (size_t)DIN_ * DM_;

    dim3 blk(256);

    // ---- single fused weight/input conversion
    {
        CvtArgs a;
        const float* srcs[7] = {x, ip_w, inproj_w, xproj_w, dtproj_w, outproj_w, op_w};
        ushort_t* dsts[7] = {xb, ipwb, inprojb, xprojb, dtprojb, outprojb, opwb};
        size_t ns[7] = {BL * DIN_, (size_t)DM_ * DIN_, (size_t)NL_ * 2 * EE * DM_,
                        (size_t)NL_ * 96 * EE, (size_t)NL_ * EE * RR,
                        (size_t)NL_ * DM_ * EE, (size_t)DIN_ * DM_};
        int cum = 0;
        for (int s = 0; s < 7; s++) {
            a.src[s] = srcs[s];
            a.dst[s] = dsts[s];
            a.cum[s] = cum;
            cum += (int)(ns[s] / 8);
        }
        a.cum[7] = cum;
        cvt_all_kernel<<<dim3((cum + 255) / 256), blk, 0, stream>>>(a);
    }

    const int PS_DM = (int)(BL * DM_);    // partial stride, DM-wide outputs

    // ---- ip: partials x2, then fused reduce(+ip_b) + LN[0]
    mgemm_kernel<5, 4, 0><<<dim3(DM_ / 64, BL / 128, 2), blk, 0, stream>>>(
        parts, xb, ipwb, nullptr, DM_, DIN_ / 2, DIN_, DIN_, DM_, PS_DM);
    reduce_ln_kernel<<<dim3(BL), blk, 0, stream>>>(
        h, hnb, parts, 2, PS_DM / 4, ip_b, ln_w, ln_b, 0);

    for (int l = 0; l < NL_; l++) {
        // xz = hn @ inproj^T (N=4096, K=1024), grid 512
        mgemm_kernel<0, 8, 1><<<dim3(2 * EE / 128, BL / 128), blk, 0, stream>>>(
            xzb, hnb, inprojb + (size_t)l * 2 * EE * DM_, nullptr,
            2 * EE, DM_, DM_, DM_, 2 * EE, 0);
        conv_silu_kernel<<<dim3(EE / 256, LL / 4, BB), blk, 0, stream>>>(
            xm, xzb, conv_w + l * EE * KK, conv_b + l * EE);
        // x_dbl partials x16 -> fused reduce (fp32 + bf16)
        mgemm_kernel<5, 8, 0><<<dim3(1, BL / 128, 16), blk, 0, stream>>>(
            parts, xm, xprojb + (size_t)l * 96 * EE, nullptr,
            96, EE / 16, EE, EE, 96, (int)(BL * 96));
        reduce_xdb_kernel<<<dim3((int)(BL * 96 / 4 + 255) / 256), blk, 0, stream>>>(
            xdb, xdbb, parts, (int)(BL * 96 / 4), (int)(BL * 96 / 4));
        // dt = softplus(xdbb[:, :64] @ dtprojb^T + b) — MFMA, 64x64 tiles
        dtmm_kernel<<<dim3(EE / 64, BL / 64), blk, 0, stream>>>(
            dtb, xdbb, dtprojb + (size_t)l * EE * RR, dtproj_b + (size_t)l * EE);

        scan_phase1_kernel<<<dim3(EE / 256, NC, BB), blk, 0, stream>>>(
            Pg, Sg, dtb, xm, xdb, A_log + (size_t)l * EE * NN);
        scan_combine_kernel<<<dim3(EE * 16 / 256, BB), blk, 0, stream>>>(Pg, Sg);
        scan_phase2_kernel<<<dim3(EE / 256, NC, BB), blk, 0, stream>>>(
            yb, Pg, dtb, xm, xdb, xzb, A_log + (size_t)l * EE * NN, Dp + l * EE);

        // outproj partials x4, then fused reduce + residual + next LN
        mgemm_kernel<5, 8, 0><<<dim3(DM_ / 128, BL / 128, 4), blk, 0, stream>>>(
            parts, yb, outprojb + (size_t)l * DM_ * EE, nullptr,
            DM_, EE / 4, EE, EE, DM_, PS_DM);
        const float* nw = (l + 1 < NL_) ? ln_w + (l + 1) * DM_ : fnorm_w;
        const float* nb = (l + 1 < NL_) ? ln_b + (l + 1) * DM_ : fnorm_b;
        reduce_ln_kernel<<<dim3(BL), blk, 0, stream>>>(
            h, hnb, parts, 4, PS_DM / 4, nullptr, nw, nb, 1);
    }

    // ---- out = hn @ op_w^T + op_b : partials x4 + fused bias reduce
    mgemm_kernel<5, 4, 0><<<dim3(DIN_ / 64, BL / 128, 4), blk, 0, stream>>>(
        parts, hnb, opwb, nullptr, DIN_, DM_ / 4, DM_, DM_, DIN_, (int)(BL * DIN_));
    reduce_bias_kernel<<<dim3((int)(BL * DIN_ / 4 + 255) / 256), blk, 0, stream>>>(
        out, parts, op_b, (int)(BL * DIN_ / 4), DIN_ / 4, (int)(BL * DIN_ / 4));
}